// Round 10
// baseline (156.230 us; speedup 1.0000x reference)
//
#include <hip/hip_runtime.h>

// MatrixFactorization: out[n] = dot(concat(Wdow[dow],Wtim[tim],Wmon[mon],Wday[day]), Witem[dest])
//
// Evidence ladder (main dur / FETCH):
//  R1 direct fp32: 91 us/297 MB   R5 bin32 fp32: 46/72   R9 bin32 bf16: ~30-33 (est, below
//  the 40-42 us harness ws-fill dispatches that now own the profiler top-5)
//  Harness constant: ~86 us of 256MB ws re-poison fills + input restores per timed iter.
// R10: (a) conversion fused INTO each bin block (R9's split grid put bin pairs on half
//      the CUs and conv pairs on the other half -> serialized phases); every CU now does
//      conv BW + bin LDS -> prep ~= 12+6 us. (b) unperm at 2 blocks/window (512 blocks).
//      (c) main: payload prefetch across the k-loop. Main's proven shape untouched.
//
// ws full (~38.5 MB): [0,32K) cntG | [32K,64K) lbaseG | [64K) Wb bf16 25.6MB
//   | payload u64 8MB | invl u16 2MB | res f32 4MB
// mid (>=14.1MB): fp32-item path.  small: direct fallback.

typedef unsigned long long u64;

constexpr int NDIM = 32;
constexpr int SZ_DOW = 7 * NDIM, SZ_TIM = 24 * NDIM, SZ_MON = 12 * NDIM, SZ_DAY = 31 * NDIM;
constexpr int B_DOW = 0;
constexpr int B_TIM = B_DOW + SZ_DOW;   // 224
constexpr int B_MON = B_TIM + SZ_TIM;   // 992
constexpr int B_DAY = B_MON + SZ_MON;   // 1376
constexpr int TAB_TOT = B_DAY + SZ_DAY; // 2368 floats

constexpr int NB     = 32;       // dest buckets (dest / 3125)
constexpr int DDIV   = 3125;
constexpr int SLICES = 256;      // bin slices
constexpr int SPB    = 4096;     // samples per slice
constexpr int BIN_T  = 1024;
constexpr int IPT    = SPB / BIN_T;  // 4

__device__ __forceinline__ unsigned short f2bf(float f) {   // RNE fp32->bf16
    const unsigned u = __float_as_uint(f);
    return (unsigned short)((u + 0x7FFFu + ((u >> 16) & 1u)) >> 16);
}

__device__ __forceinline__ float dot8bf(uint4 a, float4 u0, float4 u1) {
    float s;
    s  = __uint_as_float(a.x << 16)          * u0.x;
    s += __uint_as_float(a.x & 0xFFFF0000u)  * u0.y;
    s += __uint_as_float(a.y << 16)          * u0.z;
    s += __uint_as_float(a.y & 0xFFFF0000u)  * u0.w;
    s += __uint_as_float(a.z << 16)          * u1.x;
    s += __uint_as_float(a.z & 0xFFFF0000u)  * u1.y;
    s += __uint_as_float(a.w << 16)          * u1.z;
    s += __uint_as_float(a.w & 0xFFFF0000u)  * u1.w;
    return s;
}

__device__ __forceinline__ void load_tab(float* tab, const float* Wdow, const float* Wtim,
                                         const float* Wmon, const float* Wday, int nthr) {
    const int t = threadIdx.x;
    for (int i = t; i < SZ_DOW; i += nthr) tab[B_DOW + i] = Wdow[i];
    for (int i = t; i < SZ_TIM; i += nthr) tab[B_TIM + i] = Wtim[i];
    for (int i = t; i < SZ_MON; i += nthr) tab[B_MON + i] = Wmon[i];
    for (int i = t; i < SZ_DAY; i += nthr) tab[B_DAY + i] = Wday[i];
}

// ---------- Pass 1: bin slice b + convert chunk b of Witem (every CU does both) ----------
__global__ __launch_bounds__(BIN_T)
void prep_kernel(const int* __restrict__ dow, const int* __restrict__ tim,
                 const int* __restrict__ mon, const int* __restrict__ day,
                 const int* __restrict__ dest,
                 int* __restrict__ cntG, int* __restrict__ lbaseG,
                 u64* __restrict__ payload, unsigned short* __restrict__ invl, int n,
                 const float* __restrict__ Witem, unsigned short* __restrict__ Wb,
                 int witem_elems)
{
    __shared__ u64 stage[SPB];              // 32 KB
    __shared__ unsigned short ist[SPB];     // 8 KB
    __shared__ int hist[NB], lbase[NB], cursor[NB];

    const int t = threadIdx.x, b = blockIdx.x;
    const int g0 = b * SPB;
    const int rem = n - g0;
    const int len = rem < SPB ? rem : SPB;

    // (1) hoist bin index loads (stay in regs through the conv phase)
    int dreg[IPT], pkreg[IPT];
#pragma unroll
    for (int i = 0; i < IPT; i++) {
        const int k = i * BIN_T + t;
        if (k < len) {
            const int idx = g0 + k;
            dreg[i]  = dest[idx];
            pkreg[i] = dow[idx] | (tim[idx] << 3) | (mon[idx] << 8) | (day[idx] << 12);
        } else { dreg[i] = -1; pkreg[i] = 0; }
    }

    // (2) convert this block's contiguous chunk of Witem fp32 -> bf16
    if (Wb) {
        const int nf4   = witem_elems >> 2;                 // 3.2M float4
        const int chunk = (nf4 + SLICES - 1) / SLICES;      // 12500
        const int c0    = b * chunk;
        const int c1    = min(c0 + chunk, nf4);
        const float4* src = (const float4*)Witem;
        ushort4* dst = (ushort4*)Wb;
        for (int i = c0 + t; i < c1; i += BIN_T) {
            const float4 v = src[i];
            ushort4 o;
            o.x = f2bf(v.x); o.y = f2bf(v.y); o.z = f2bf(v.z); o.w = f2bf(v.w);
            dst[i] = o;
        }
    }

    // (3) bin LDS phases
    if (t < NB) hist[t] = 0;
    __syncthreads();
#pragma unroll
    for (int i = 0; i < IPT; i++)
        if (dreg[i] >= 0) atomicAdd(&hist[dreg[i] / DDIV], 1);
    __syncthreads();
    if (t == 0) {
        int run = 0;
        for (int q = 0; q < NB; q++) { lbase[q] = run; run += hist[q]; }
    }
    __syncthreads();
    if (t < NB) { cursor[t] = lbase[t]; cntG[b * NB + t] = hist[t]; lbaseG[b * NB + t] = lbase[t]; }
    __syncthreads();
#pragma unroll
    for (int i = 0; i < IPT; i++) {
        const int k = i * BIN_T + t;
        if (k < len) {
            const int j = atomicAdd(&cursor[dreg[i] / DDIV], 1);   // LDS atomic only
            stage[j] = (u64)(unsigned)(g0 + k)
                     | ((u64)(unsigned)dreg[i]  << 20)
                     | ((u64)(unsigned)pkreg[i] << 37);
            ist[k] = (unsigned short)j;
        }
    }
    __syncthreads();
#pragma unroll
    for (int i = 0; i < IPT; i++) {
        const int k = i * BIN_T + t;
        if (k < len) {
            payload[g0 + k] = stage[k];    // coalesced
            invl[g0 + k]    = ist[k];      // coalesced
        }
    }
}

// ---------- Pass 2 (full): XCD-phased binned dot, bf16 items ----------
__global__ __launch_bounds__(256, 8)
void mf_main_bf16(const u64* __restrict__ payload,
                  const float* __restrict__ Wdow, const float* __restrict__ Wtim,
                  const float* __restrict__ Wmon, const float* __restrict__ Wday,
                  const unsigned short* __restrict__ Wb,
                  const int* __restrict__ cntG, const int* __restrict__ lbaseG,
                  float* __restrict__ res)
{
    __shared__ float tab[TAB_TOT];
    load_tab(tab, Wdow, Wtim, Wmon, Wday, 256);
    __syncthreads();

    const int tid = threadIdx.x;
    const int sub = tid & 63;
    const int wv  = tid >> 6;       // wave 0..3
    const int g   = sub >> 3;       // 8-lane group 0..7
    const int l8  = sub & 7;
    const int jt   = l8 >> 1;           // table id
    const int half = (l8 & 1) * 16;     // 16-dim half within table
    const int tbj  = (jt == 0) ? B_DOW : (jt == 1) ? B_TIM : (jt == 2) ? B_MON : B_DAY;
    const int shj  = (jt == 0) ? 37    : (jt == 1) ? 40    : (jt == 2) ? 45    : 49;
    const int mkj  = (jt == 0) ? 7     : (jt == 1) ? 31    : (jt == 2) ? 15    : 31;

    const int x = blockIdx.x & 7;   // intended XCD
    const int s = blockIdx.x >> 3;  // slice 0..255

    for (int p = 0; p < 4; p++) {
        const int q  = x + 8 * p;
        const int L  = cntG[s * NB + q];
        const int st = s * SPB + lbaseG[s * NB + q];

        int i = wv * 16;
        // prefetch first iteration's payloads
        u64 p0 = (i + g < L)     ? payload[st + i + g]     : 0ull;
        u64 p1 = (i + 8 + g < L) ? payload[st + i + 8 + g] : 0ull;

        for (; i < L; i += 64) {
            const int i0 = i + g, i1 = i + 8 + g;
            const bool v0 = i0 < L, v1 = i1 < L;
            const u64 c0 = p0, c1 = p1;
            // prefetch next iteration's payloads (overlaps item fetch below)
            const int ni = i + 64;
            p0 = (ni + g < L)     ? payload[st + ni + g]     : 0ull;
            p1 = (ni + 8 + g < L) ? payload[st + ni + 8 + g] : 0ull;

            const int d0 = (int)((c0 >> 20) & 0x1FFFFull);
            const int d1 = (int)((c1 >> 20) & 0x1FFFFull);

            const uint4* r0 = (const uint4*)(Wb + (long)d0 * 128 + (l8 << 4));
            const uint4* r1 = (const uint4*)(Wb + (long)d1 * 128 + (l8 << 4));
            const uint4 A0 = r0[0], B0 = r0[1];
            const uint4 A1 = r1[0], B1 = r1[1];

            const int ix0 = (int)((c0 >> shj) & (u64)mkj);
            const int ix1 = (int)((c1 >> shj) & (u64)mkj);
            const float* u0p = &tab[tbj + ix0 * NDIM + half];
            const float* u1p = &tab[tbj + ix1 * NDIM + half];
            const float4 u00 = *(const float4*)(u0p);
            const float4 u01 = *(const float4*)(u0p + 4);
            const float4 u02 = *(const float4*)(u0p + 8);
            const float4 u03 = *(const float4*)(u0p + 12);
            const float4 u10 = *(const float4*)(u1p);
            const float4 u11 = *(const float4*)(u1p + 4);
            const float4 u12 = *(const float4*)(u1p + 8);
            const float4 u13 = *(const float4*)(u1p + 12);

            float a0 = dot8bf(A0, u00, u01) + dot8bf(B0, u02, u03);
            float a1 = dot8bf(A1, u10, u11) + dot8bf(B1, u12, u13);

            a0 += __shfl_xor(a0, 1);  a1 += __shfl_xor(a1, 1);
            a0 += __shfl_xor(a0, 2);  a1 += __shfl_xor(a1, 2);
            a0 += __shfl_xor(a0, 4);  a1 += __shfl_xor(a1, 4);

            if (l8 == 0) {              // coalesced, payload-order
                if (v0) res[st + i0] = a0;
                if (v1) res[st + i1] = a1;
            }
        }
    }
}

// ---------- Pass 2 (mid): fp32 items ----------
__global__ __launch_bounds__(256, 8)
void mf_main_f32(const u64* __restrict__ payload,
                 const float* __restrict__ Wdow, const float* __restrict__ Wtim,
                 const float* __restrict__ Wmon, const float* __restrict__ Wday,
                 const float* __restrict__ Witem,
                 const int* __restrict__ cntG, const int* __restrict__ lbaseG,
                 float* __restrict__ res)
{
    __shared__ float tab[TAB_TOT];
    load_tab(tab, Wdow, Wtim, Wmon, Wday, 256);
    __syncthreads();
    const int tid = threadIdx.x;
    const int sub = tid & 63;
    const int wv  = tid >> 6;
    const int g   = sub >> 3;
    const int l8  = sub & 7;
    const int col = l8 * 4;
    const int tb[4] = {B_DOW, B_TIM, B_MON, B_DAY};
    const int sh[4] = {37, 40, 45, 49};
    const int mk[4] = {7, 31, 15, 31};
    const int x = blockIdx.x & 7;
    const int s = blockIdx.x >> 3;
    for (int p = 0; p < 4; p++) {
        const int q  = x + 8 * p;
        const int L  = cntG[s * NB + q];
        const int st = s * SPB + lbaseG[s * NB + q];
        for (int i = wv * 16; i < L; i += 64) {
            const int i0 = i + g, i1 = i + 8 + g;
            const bool v0 = i0 < L, v1 = i1 < L;
            const u64 p0 = v0 ? payload[st + i0] : 0ull;
            const u64 p1 = v1 ? payload[st + i1] : 0ull;
            const int d0 = (int)((p0 >> 20) & 0x1FFFFull);
            const int d1 = (int)((p1 >> 20) & 0x1FFFFull);
            const float* r0 = Witem + (long)d0 * 128 + col;
            const float* r1 = Witem + (long)d1 * 128 + col;
            float4 it0[4], it1[4], us0[4], us1[4];
#pragma unroll
            for (int j = 0; j < 4; j++) it0[j] = *reinterpret_cast<const float4*>(r0 + j * NDIM);
#pragma unroll
            for (int j = 0; j < 4; j++) it1[j] = *reinterpret_cast<const float4*>(r1 + j * NDIM);
#pragma unroll
            for (int j = 0; j < 4; j++) {
                const int idx = (int)((p0 >> sh[j]) & (u64)mk[j]);
                us0[j] = *reinterpret_cast<const float4*>(&tab[tb[j] + idx * NDIM + col]);
            }
#pragma unroll
            for (int j = 0; j < 4; j++) {
                const int idx = (int)((p1 >> sh[j]) & (u64)mk[j]);
                us1[j] = *reinterpret_cast<const float4*>(&tab[tb[j] + idx * NDIM + col]);
            }
            float a0 = 0.f, a1 = 0.f;
#pragma unroll
            for (int j = 0; j < 4; j++) {
                a0 += it0[j].x * us0[j].x + it0[j].y * us0[j].y
                    + it0[j].z * us0[j].z + it0[j].w * us0[j].w;
                a1 += it1[j].x * us1[j].x + it1[j].y * us1[j].y
                    + it1[j].z * us1[j].z + it1[j].w * us1[j].w;
            }
            a0 += __shfl_xor(a0, 1);  a1 += __shfl_xor(a1, 1);
            a0 += __shfl_xor(a0, 2);  a1 += __shfl_xor(a1, 2);
            a0 += __shfl_xor(a0, 4);  a1 += __shfl_xor(a1, 4);
            if (l8 == 0) {
                if (v0) res[st + i0] = a0;
                if (v1) res[st + i1] = a1;
            }
        }
    }
}

// ---------- Pass 3: unpermute res -> out; 2 blocks per 4096-window ----------
__global__ __launch_bounds__(BIN_T)
void unperm_kernel(const float* __restrict__ res, const unsigned short* __restrict__ invl,
                   float* __restrict__ out, int n)
{
    __shared__ float r[SPB];    // 16 KB
    const int t = threadIdx.x;
    const int w = blockIdx.x >> 1;      // window 0..255
    const int h = blockIdx.x & 1;       // half 0/1
    const int g0 = w * SPB;
    const int rem = n - g0;
    const int len = rem < SPB ? rem : SPB;

    // whole window into LDS (both halves need arbitrary sources)
#pragma unroll
    for (int i = 0; i < IPT; i++) {
        const int k = i * BIN_T + t;
        if (k < len) r[k] = res[g0 + k];
    }
    // this block's half of the outputs
    const int o0 = h * (SPB / 2);
    unsigned short iv[IPT / 2];
#pragma unroll
    for (int i = 0; i < IPT / 2; i++) {
        const int k = o0 + i * BIN_T + t;
        iv[i] = (k < len) ? invl[g0 + k] : 0;
    }
    __syncthreads();
#pragma unroll
    for (int i = 0; i < IPT / 2; i++) {
        const int k = o0 + i * BIN_T + t;
        if (k < len) out[g0 + k] = r[iv[i]];
    }
}

// ---------- Fallback: direct fp32 ----------
__global__ __launch_bounds__(256, 8)
void mf_dot_kernel(const int* __restrict__ dow, const int* __restrict__ tim,
                   const int* __restrict__ mon, const int* __restrict__ day,
                   const int* __restrict__ dest,
                   const float* __restrict__ Wdow, const float* __restrict__ Wtim,
                   const float* __restrict__ Wmon, const float* __restrict__ Wday,
                   const float* __restrict__ Witem,
                   float* __restrict__ out, int n_samples)
{
    __shared__ float tab[TAB_TOT];
    load_tab(tab, Wdow, Wtim, Wmon, Wday, 256);
    __syncthreads();
    const int tid = threadIdx.x;
    const int lane = tid & 63, sub = lane & 31, wave = tid >> 6, half = lane >> 5;
    const int t = sub >> 3, dofs = (sub & 7) * 4;
    const int* idxp  = (t == 0) ? dow   : (t == 1) ? tim   : (t == 2) ? mon   : day;
    const int  tbase = (t == 0) ? B_DOW : (t == 1) ? B_TIM : (t == 2) ? B_MON : B_DAY;
    long n = (long)blockIdx.x * 8 + wave * 2 + half;
    const long stride = (long)gridDim.x * 8;
    for (; n < n_samples; n += stride) {
        const int idx = idxp[n];
        const int ds  = dest[n];
        const float4 u  = *reinterpret_cast<const float4*>(&tab[tbase + idx * NDIM + dofs]);
        const float4 it = *reinterpret_cast<const float4*>(&Witem[(long)ds * 128 + sub * 4]);
        float r = u.x * it.x + u.y * it.y + u.z * it.z + u.w * it.w;
        r += __shfl_xor(r, 16); r += __shfl_xor(r, 8); r += __shfl_xor(r, 4);
        r += __shfl_xor(r, 2);  r += __shfl_xor(r, 1);
        if (sub == 0) out[n] = r;
    }
}

extern "C" void kernel_launch(void* const* d_in, const int* in_sizes, int n_in,
                              void* d_out, int out_size, void* d_ws, size_t ws_size,
                              hipStream_t stream)
{
    const int*   dow   = (const int*)d_in[0];
    const int*   tim   = (const int*)d_in[1];
    const int*   mon   = (const int*)d_in[2];
    const int*   day   = (const int*)d_in[3];
    const int*   dest  = (const int*)d_in[4];
    const float* Wdow  = (const float*)d_in[5];
    const float* Wtim  = (const float*)d_in[6];
    const float* Wmon  = (const float*)d_in[7];
    const float* Wday  = (const float*)d_in[8];
    const float* Witem = (const float*)d_in[9];
    float* out = (float*)d_out;

    const int n  = in_sizes[0];      // 1048576
    const int we = in_sizes[9];      // 12,800,000
    const int cap = SLICES * SPB;    // 1<<20

    const size_t off_wb       = 64 * 1024;
    const size_t off_pay_full = (off_wb + (size_t)we * 2 + 255) & ~(size_t)255;
    const size_t off_inv_full = off_pay_full + (size_t)cap * 8;
    const size_t off_res_full = off_inv_full + (size_t)cap * 2;
    const size_t need_full    = off_res_full + (size_t)cap * 4;   // ~38.5 MB
    const size_t off_pay_mid  = 64 * 1024;
    const size_t off_inv_mid  = off_pay_mid + (size_t)cap * 8;
    const size_t off_res_mid  = off_inv_mid + (size_t)cap * 2;
    const size_t need_mid     = off_res_mid + (size_t)cap * 4;    // ~14.1 MB

    if ((size_t)ws_size < need_mid || n > cap) {
        hipLaunchKernelGGL(mf_dot_kernel, dim3(2048), dim3(256), 0, stream,
                           dow, tim, mon, day, dest,
                           Wdow, Wtim, Wmon, Wday, Witem, out, n);
        return;
    }

    const bool full = (size_t)ws_size >= need_full;

    int* cntG   = (int*)d_ws;
    int* lbaseG = (int*)((char*)d_ws + 32 * 1024);
    unsigned short* Wb = full ? (unsigned short*)((char*)d_ws + off_wb) : nullptr;
    u64* payload = (u64*)((char*)d_ws + (full ? off_pay_full : off_pay_mid));
    unsigned short* invl = (unsigned short*)((char*)d_ws + (full ? off_inv_full : off_inv_mid));
    float* res           = (float*)((char*)d_ws + (full ? off_res_full : off_res_mid));

    hipLaunchKernelGGL(prep_kernel, dim3(SLICES), dim3(BIN_T), 0, stream,
                       dow, tim, mon, day, dest, cntG, lbaseG, payload, invl, n,
                       Witem, Wb, we);
    if (full)
        hipLaunchKernelGGL(mf_main_bf16, dim3(SLICES * 8), dim3(256), 0, stream,
                           payload, Wdow, Wtim, Wmon, Wday, Wb, cntG, lbaseG, res);
    else
        hipLaunchKernelGGL(mf_main_f32, dim3(SLICES * 8), dim3(256), 0, stream,
                           payload, Wdow, Wtim, Wmon, Wday, Witem, cntG, lbaseG, res);
    hipLaunchKernelGGL(unperm_kernel, dim3(SLICES * 2), dim3(BIN_T), 0, stream,
                       res, invl, out, n);
}

// Round 11
// 151.404 us; speedup vs baseline: 1.0319x; 1.0319x over previous
//
#include <hip/hip_runtime.h>

// MatrixFactorization: out[n] = dot(concat(Wdow[dow],Wtim[tim],Wmon[mon],Wday[day]), Witem[dest])
//
// Evidence ladder (bench dur): R1 direct fp32 186 -> R5 bin32 fp32 168 -> R9 bin32 bf16 153.
// Profiler top-5 is now 100% harness ws re-poison (256MB fill @6.5TB/s = 42us) — the
// bench has a ~50us fixed harness constant; our pipeline is the remainder.
// R11: delete the res/unperm pass. It existed because R4's scattered out[id] writes
// showed 32MB write-amp — but that amp was L2 thrash from 512B/sample fp32 item
// traffic. With bf16 items (0.8MB/XCD working set) and per-slice-local ids (each
// main block's out writes land in ONE 16KB window), dirty lines accumulate and
// drain once. Direct out[id] write from main => -1 kernel, -6MB ws traffic,
// -2MB invl write in prep. Everything else = R10.
//
// ws full (~33.8 MB): [0,32K) cntG | [32K,64K) lbaseG | [64K) Wb bf16 25.6MB | payload u64 8MB
// mid (>=8.07MB): fp32-item path.  small: direct fallback.

typedef unsigned long long u64;

constexpr int NDIM = 32;
constexpr int SZ_DOW = 7 * NDIM, SZ_TIM = 24 * NDIM, SZ_MON = 12 * NDIM, SZ_DAY = 31 * NDIM;
constexpr int B_DOW = 0;
constexpr int B_TIM = B_DOW + SZ_DOW;   // 224
constexpr int B_MON = B_TIM + SZ_TIM;   // 992
constexpr int B_DAY = B_MON + SZ_MON;   // 1376
constexpr int TAB_TOT = B_DAY + SZ_DAY; // 2368 floats

constexpr int NB     = 32;       // dest buckets (dest / 3125)
constexpr int DDIV   = 3125;
constexpr int SLICES = 256;      // bin slices
constexpr int SPB    = 4096;     // samples per slice
constexpr int BIN_T  = 1024;
constexpr int IPT    = SPB / BIN_T;  // 4

__device__ __forceinline__ unsigned short f2bf(float f) {   // RNE fp32->bf16
    const unsigned u = __float_as_uint(f);
    return (unsigned short)((u + 0x7FFFu + ((u >> 16) & 1u)) >> 16);
}

__device__ __forceinline__ float dot8bf(uint4 a, float4 u0, float4 u1) {
    float s;
    s  = __uint_as_float(a.x << 16)          * u0.x;
    s += __uint_as_float(a.x & 0xFFFF0000u)  * u0.y;
    s += __uint_as_float(a.y << 16)          * u0.z;
    s += __uint_as_float(a.y & 0xFFFF0000u)  * u0.w;
    s += __uint_as_float(a.z << 16)          * u1.x;
    s += __uint_as_float(a.z & 0xFFFF0000u)  * u1.y;
    s += __uint_as_float(a.w << 16)          * u1.z;
    s += __uint_as_float(a.w & 0xFFFF0000u)  * u1.w;
    return s;
}

__device__ __forceinline__ void load_tab(float* tab, const float* Wdow, const float* Wtim,
                                         const float* Wmon, const float* Wday, int nthr) {
    const int t = threadIdx.x;
    for (int i = t; i < SZ_DOW; i += nthr) tab[B_DOW + i] = Wdow[i];
    for (int i = t; i < SZ_TIM; i += nthr) tab[B_TIM + i] = Wtim[i];
    for (int i = t; i < SZ_MON; i += nthr) tab[B_MON + i] = Wmon[i];
    for (int i = t; i < SZ_DAY; i += nthr) tab[B_DAY + i] = Wday[i];
}

// ---------- Pass 1: bin slice b + convert chunk b of Witem (every CU does both) ----------
__global__ __launch_bounds__(BIN_T)
void prep_kernel(const int* __restrict__ dow, const int* __restrict__ tim,
                 const int* __restrict__ mon, const int* __restrict__ day,
                 const int* __restrict__ dest,
                 int* __restrict__ cntG, int* __restrict__ lbaseG,
                 u64* __restrict__ payload, int n,
                 const float* __restrict__ Witem, unsigned short* __restrict__ Wb,
                 int witem_elems)
{
    __shared__ u64 stage[SPB];              // 32 KB
    __shared__ int hist[NB], lbase[NB], cursor[NB];

    const int t = threadIdx.x, b = blockIdx.x;
    const int g0 = b * SPB;
    const int rem = n - g0;
    const int len = rem < SPB ? rem : SPB;

    // (1) hoist bin index loads
    int dreg[IPT], pkreg[IPT];
#pragma unroll
    for (int i = 0; i < IPT; i++) {
        const int k = i * BIN_T + t;
        if (k < len) {
            const int idx = g0 + k;
            dreg[i]  = dest[idx];
            pkreg[i] = dow[idx] | (tim[idx] << 3) | (mon[idx] << 8) | (day[idx] << 12);
        } else { dreg[i] = -1; pkreg[i] = 0; }
    }

    // (2) convert this block's contiguous chunk of Witem fp32 -> bf16
    if (Wb) {
        const int nf4   = witem_elems >> 2;                 // 3.2M float4
        const int chunk = (nf4 + SLICES - 1) / SLICES;      // 12500
        const int c0    = b * chunk;
        const int c1    = min(c0 + chunk, nf4);
        const float4* src = (const float4*)Witem;
        ushort4* dst = (ushort4*)Wb;
        for (int i = c0 + t; i < c1; i += BIN_T) {
            const float4 v = src[i];
            ushort4 o;
            o.x = f2bf(v.x); o.y = f2bf(v.y); o.z = f2bf(v.z); o.w = f2bf(v.w);
            dst[i] = o;
        }
    }

    // (3) bin LDS phases
    if (t < NB) hist[t] = 0;
    __syncthreads();
#pragma unroll
    for (int i = 0; i < IPT; i++)
        if (dreg[i] >= 0) atomicAdd(&hist[dreg[i] / DDIV], 1);
    __syncthreads();
    if (t == 0) {
        int run = 0;
        for (int q = 0; q < NB; q++) { lbase[q] = run; run += hist[q]; }
    }
    __syncthreads();
    if (t < NB) { cursor[t] = lbase[t]; cntG[b * NB + t] = hist[t]; lbaseG[b * NB + t] = lbase[t]; }
    __syncthreads();
#pragma unroll
    for (int i = 0; i < IPT; i++) {
        const int k = i * BIN_T + t;
        if (k < len) {
            const int j = atomicAdd(&cursor[dreg[i] / DDIV], 1);   // LDS atomic only
            stage[j] = (u64)(unsigned)(g0 + k)
                     | ((u64)(unsigned)dreg[i]  << 20)
                     | ((u64)(unsigned)pkreg[i] << 37);
        }
    }
    __syncthreads();
#pragma unroll
    for (int i = 0; i < IPT; i++) {
        const int k = i * BIN_T + t;
        if (k < len) payload[g0 + k] = stage[k];   // coalesced
    }
}

// ---------- Pass 2 (full): XCD-phased binned dot, bf16 items, direct out writes ----------
__global__ __launch_bounds__(256, 8)
void mf_main_bf16(const u64* __restrict__ payload,
                  const float* __restrict__ Wdow, const float* __restrict__ Wtim,
                  const float* __restrict__ Wmon, const float* __restrict__ Wday,
                  const unsigned short* __restrict__ Wb,
                  const int* __restrict__ cntG, const int* __restrict__ lbaseG,
                  float* __restrict__ out)
{
    __shared__ float tab[TAB_TOT];
    load_tab(tab, Wdow, Wtim, Wmon, Wday, 256);
    __syncthreads();

    const int tid = threadIdx.x;
    const int sub = tid & 63;
    const int wv  = tid >> 6;       // wave 0..3
    const int g   = sub >> 3;       // 8-lane group 0..7
    const int l8  = sub & 7;
    const int jt   = l8 >> 1;           // table id
    const int half = (l8 & 1) * 16;     // 16-dim half within table
    const int tbj  = (jt == 0) ? B_DOW : (jt == 1) ? B_TIM : (jt == 2) ? B_MON : B_DAY;
    const int shj  = (jt == 0) ? 37    : (jt == 1) ? 40    : (jt == 2) ? 45    : 49;
    const int mkj  = (jt == 0) ? 7     : (jt == 1) ? 31    : (jt == 2) ? 15    : 31;

    const int x = blockIdx.x & 7;   // intended XCD
    const int s = blockIdx.x >> 3;  // slice 0..255

    for (int p = 0; p < 4; p++) {
        const int q  = x + 8 * p;
        const int L  = cntG[s * NB + q];
        const int st = s * SPB + lbaseG[s * NB + q];

        int i = wv * 16;
        u64 p0 = (i + g < L)     ? payload[st + i + g]     : 0ull;
        u64 p1 = (i + 8 + g < L) ? payload[st + i + 8 + g] : 0ull;

        for (; i < L; i += 64) {
            const bool v0 = (i + g) < L, v1 = (i + 8 + g) < L;
            const u64 c0 = p0, c1 = p1;
            const int ni = i + 64;
            p0 = (ni + g < L)     ? payload[st + ni + g]     : 0ull;
            p1 = (ni + 8 + g < L) ? payload[st + ni + 8 + g] : 0ull;

            const int d0 = (int)((c0 >> 20) & 0x1FFFFull);
            const int d1 = (int)((c1 >> 20) & 0x1FFFFull);

            const uint4* r0 = (const uint4*)(Wb + (long)d0 * 128 + (l8 << 4));
            const uint4* r1 = (const uint4*)(Wb + (long)d1 * 128 + (l8 << 4));
            const uint4 A0 = r0[0], B0 = r0[1];
            const uint4 A1 = r1[0], B1 = r1[1];

            const int ix0 = (int)((c0 >> shj) & (u64)mkj);
            const int ix1 = (int)((c1 >> shj) & (u64)mkj);
            const float* u0p = &tab[tbj + ix0 * NDIM + half];
            const float* u1p = &tab[tbj + ix1 * NDIM + half];
            const float4 u00 = *(const float4*)(u0p);
            const float4 u01 = *(const float4*)(u0p + 4);
            const float4 u02 = *(const float4*)(u0p + 8);
            const float4 u03 = *(const float4*)(u0p + 12);
            const float4 u10 = *(const float4*)(u1p);
            const float4 u11 = *(const float4*)(u1p + 4);
            const float4 u12 = *(const float4*)(u1p + 8);
            const float4 u13 = *(const float4*)(u1p + 12);

            float a0 = dot8bf(A0, u00, u01) + dot8bf(B0, u02, u03);
            float a1 = dot8bf(A1, u10, u11) + dot8bf(B1, u12, u13);

            a0 += __shfl_xor(a0, 1);  a1 += __shfl_xor(a1, 1);
            a0 += __shfl_xor(a0, 2);  a1 += __shfl_xor(a1, 2);
            a0 += __shfl_xor(a0, 4);  a1 += __shfl_xor(a1, 4);

            if (l8 == 0) {  // direct out write; ids are slice-local -> one 16KB window/block
                if (v0) out[(int)(c0 & 0xFFFFFull)] = a0;
                if (v1) out[(int)(c1 & 0xFFFFFull)] = a1;
            }
        }
    }
}

// ---------- Pass 2 (mid): fp32 items, direct out writes ----------
__global__ __launch_bounds__(256, 8)
void mf_main_f32(const u64* __restrict__ payload,
                 const float* __restrict__ Wdow, const float* __restrict__ Wtim,
                 const float* __restrict__ Wmon, const float* __restrict__ Wday,
                 const float* __restrict__ Witem,
                 const int* __restrict__ cntG, const int* __restrict__ lbaseG,
                 float* __restrict__ out)
{
    __shared__ float tab[TAB_TOT];
    load_tab(tab, Wdow, Wtim, Wmon, Wday, 256);
    __syncthreads();
    const int tid = threadIdx.x;
    const int sub = tid & 63;
    const int wv  = tid >> 6;
    const int g   = sub >> 3;
    const int l8  = sub & 7;
    const int col = l8 * 4;
    const int tb[4] = {B_DOW, B_TIM, B_MON, B_DAY};
    const int sh[4] = {37, 40, 45, 49};
    const int mk[4] = {7, 31, 15, 31};
    const int x = blockIdx.x & 7;
    const int s = blockIdx.x >> 3;
    for (int p = 0; p < 4; p++) {
        const int q  = x + 8 * p;
        const int L  = cntG[s * NB + q];
        const int st = s * SPB + lbaseG[s * NB + q];
        for (int i = wv * 16; i < L; i += 64) {
            const int i0 = i + g, i1 = i + 8 + g;
            const bool v0 = i0 < L, v1 = i1 < L;
            const u64 p0 = v0 ? payload[st + i0] : 0ull;
            const u64 p1 = v1 ? payload[st + i1] : 0ull;
            const int d0 = (int)((p0 >> 20) & 0x1FFFFull);
            const int d1 = (int)((p1 >> 20) & 0x1FFFFull);
            const float* r0 = Witem + (long)d0 * 128 + col;
            const float* r1 = Witem + (long)d1 * 128 + col;
            float4 it0[4], it1[4], us0[4], us1[4];
#pragma unroll
            for (int j = 0; j < 4; j++) it0[j] = *reinterpret_cast<const float4*>(r0 + j * NDIM);
#pragma unroll
            for (int j = 0; j < 4; j++) it1[j] = *reinterpret_cast<const float4*>(r1 + j * NDIM);
#pragma unroll
            for (int j = 0; j < 4; j++) {
                const int idx = (int)((p0 >> sh[j]) & (u64)mk[j]);
                us0[j] = *reinterpret_cast<const float4*>(&tab[tb[j] + idx * NDIM + col]);
            }
#pragma unroll
            for (int j = 0; j < 4; j++) {
                const int idx = (int)((p1 >> sh[j]) & (u64)mk[j]);
                us1[j] = *reinterpret_cast<const float4*>(&tab[tb[j] + idx * NDIM + col]);
            }
            float a0 = 0.f, a1 = 0.f;
#pragma unroll
            for (int j = 0; j < 4; j++) {
                a0 += it0[j].x * us0[j].x + it0[j].y * us0[j].y
                    + it0[j].z * us0[j].z + it0[j].w * us0[j].w;
                a1 += it1[j].x * us1[j].x + it1[j].y * us1[j].y
                    + it1[j].z * us1[j].z + it1[j].w * us1[j].w;
            }
            a0 += __shfl_xor(a0, 1);  a1 += __shfl_xor(a1, 1);
            a0 += __shfl_xor(a0, 2);  a1 += __shfl_xor(a1, 2);
            a0 += __shfl_xor(a0, 4);  a1 += __shfl_xor(a1, 4);
            if (l8 == 0) {
                if (v0) out[(int)(p0 & 0xFFFFFull)] = a0;
                if (v1) out[(int)(p1 & 0xFFFFFull)] = a1;
            }
        }
    }
}

// ---------- Fallback: direct fp32 ----------
__global__ __launch_bounds__(256, 8)
void mf_dot_kernel(const int* __restrict__ dow, const int* __restrict__ tim,
                   const int* __restrict__ mon, const int* __restrict__ day,
                   const int* __restrict__ dest,
                   const float* __restrict__ Wdow, const float* __restrict__ Wtim,
                   const float* __restrict__ Wmon, const float* __restrict__ Wday,
                   const float* __restrict__ Witem,
                   float* __restrict__ out, int n_samples)
{
    __shared__ float tab[TAB_TOT];
    load_tab(tab, Wdow, Wtim, Wmon, Wday, 256);
    __syncthreads();
    const int tid = threadIdx.x;
    const int lane = tid & 63, sub = lane & 31, wave = tid >> 6, half = lane >> 5;
    const int t = sub >> 3, dofs = (sub & 7) * 4;
    const int* idxp  = (t == 0) ? dow   : (t == 1) ? tim   : (t == 2) ? mon   : day;
    const int  tbase = (t == 0) ? B_DOW : (t == 1) ? B_TIM : (t == 2) ? B_MON : B_DAY;
    long n = (long)blockIdx.x * 8 + wave * 2 + half;
    const long stride = (long)gridDim.x * 8;
    for (; n < n_samples; n += stride) {
        const int idx = idxp[n];
        const int ds  = dest[n];
        const float4 u  = *reinterpret_cast<const float4*>(&tab[tbase + idx * NDIM + dofs]);
        const float4 it = *reinterpret_cast<const float4*>(&Witem[(long)ds * 128 + sub * 4]);
        float r = u.x * it.x + u.y * it.y + u.z * it.z + u.w * it.w;
        r += __shfl_xor(r, 16); r += __shfl_xor(r, 8); r += __shfl_xor(r, 4);
        r += __shfl_xor(r, 2);  r += __shfl_xor(r, 1);
        if (sub == 0) out[n] = r;
    }
}

extern "C" void kernel_launch(void* const* d_in, const int* in_sizes, int n_in,
                              void* d_out, int out_size, void* d_ws, size_t ws_size,
                              hipStream_t stream)
{
    const int*   dow   = (const int*)d_in[0];
    const int*   tim   = (const int*)d_in[1];
    const int*   mon   = (const int*)d_in[2];
    const int*   day   = (const int*)d_in[3];
    const int*   dest  = (const int*)d_in[4];
    const float* Wdow  = (const float*)d_in[5];
    const float* Wtim  = (const float*)d_in[6];
    const float* Wmon  = (const float*)d_in[7];
    const float* Wday  = (const float*)d_in[8];
    const float* Witem = (const float*)d_in[9];
    float* out = (float*)d_out;

    const int n  = in_sizes[0];      // 1048576
    const int we = in_sizes[9];      // 12,800,000
    const int cap = SLICES * SPB;    // 1<<20

    const size_t off_wb       = 64 * 1024;
    const size_t off_pay_full = (off_wb + (size_t)we * 2 + 255) & ~(size_t)255;
    const size_t need_full    = off_pay_full + (size_t)cap * 8;   // ~33.8 MB
    const size_t off_pay_mid  = 64 * 1024;
    const size_t need_mid     = off_pay_mid + (size_t)cap * 8;    // ~8.07 MB

    if ((size_t)ws_size < need_mid || n > cap) {
        hipLaunchKernelGGL(mf_dot_kernel, dim3(2048), dim3(256), 0, stream,
                           dow, tim, mon, day, dest,
                           Wdow, Wtim, Wmon, Wday, Witem, out, n);
        return;
    }

    const bool full = (size_t)ws_size >= need_full;

    int* cntG   = (int*)d_ws;
    int* lbaseG = (int*)((char*)d_ws + 32 * 1024);
    unsigned short* Wb = full ? (unsigned short*)((char*)d_ws + off_wb) : nullptr;
    u64* payload = (u64*)((char*)d_ws + (full ? off_pay_full : off_pay_mid));

    hipLaunchKernelGGL(prep_kernel, dim3(SLICES), dim3(BIN_T), 0, stream,
                       dow, tim, mon, day, dest, cntG, lbaseG, payload, n,
                       Witem, Wb, we);
    if (full)
        hipLaunchKernelGGL(mf_main_bf16, dim3(SLICES * 8), dim3(256), 0, stream,
                           payload, Wdow, Wtim, Wmon, Wday, Wb, cntG, lbaseG, out);
    else
        hipLaunchKernelGGL(mf_main_f32, dim3(SLICES * 8), dim3(256), 0, stream,
                           payload, Wdow, Wtim, Wmon, Wday, Witem, cntG, lbaseG, out);
}